// Round 15
// baseline (144.599 us; speedup 1.0000x reference)
//
#include <hip/hip_runtime.h>
#include <hip/hip_bf16.h>

// NerTr fused pipeline for MI355X (gfx950).  B=32, S=512, D=768, C=25.
// ws layout (bytes):
//   decb  (bf16 32*25*768)    [0, 1228800)
//   wtb   (bf16 25*768)       [1228800, 1267200)
//   nprob (f32 32*512*25)     [1305600, 2944000)
//   csp   (f32 32*512*25)     [2944000, 4582400)
//   traceF(f32 32*16448)      [4582400, 6687744)   viterbi fwd states, stride 64/step
//   traceB(f32 32*16448)      [6687744, 8793088)   viterbi bwd suffix states, stride 64
// out: [0]=loss (f32), [1 + b*512 + t] = viterbi tag (as f32).

#define NEGINF (-1e30f)

__device__ __forceinline__ float rlane(float x, int i) {
  return __int_as_float(__builtin_amdgcn_readlane(__float_as_int(x), i));
}
__device__ __forceinline__ float rfl(float x) {
  return __int_as_float(__builtin_amdgcn_readfirstlane(__float_as_int(x)));
}
template <int CTRL, int RMASK>
__device__ __forceinline__ float dppAdd(float x) {
  return x + __int_as_float(__builtin_amdgcn_update_dpp(
                 0, __float_as_int(x), CTRL, RMASK, 0xF, true));
}
__device__ __forceinline__ float wsum(float v) {
  v = dppAdd<0x111, 0xF>(v);
  v = dppAdd<0x112, 0xF>(v);
  v = dppAdd<0x114, 0xF>(v);
  v = dppAdd<0x118, 0xF>(v);
  v = dppAdd<0x142, 0xA>(v);
  v = dppAdd<0x143, 0xC>(v);
  return rlane(v, 63);
}
__device__ __forceinline__ ushort f2bf(float x) {
  __hip_bfloat16 h = __float2bfloat16(x);
  return *reinterpret_cast<ushort*>(&h);
}
__device__ __forceinline__ void ld12(float* x, const float* p, int lane) {
#pragma unroll
  for (int k = 0; k < 3; k++) {
    float4 v = *(const float4*)(p + (lane + (k << 6)) * 4);
    x[4 * k + 0] = v.x; x[4 * k + 1] = v.y; x[4 * k + 2] = v.z; x[4 * k + 3] = v.w;
  }
}
__device__ __forceinline__ void ld12bf(float* x, const ushort* row, int lane) {
  uint2 d0 = *(const uint2*)((const char*)row + lane * 8);
  uint2 d1 = *(const uint2*)((const char*)row + lane * 8 + 512);
  uint2 d2 = *(const uint2*)((const char*)row + lane * 8 + 1024);
  x[0]  = __uint_as_float(d0.x << 16); x[1]  = __uint_as_float(d0.x & 0xffff0000u);
  x[2]  = __uint_as_float(d0.y << 16); x[3]  = __uint_as_float(d0.y & 0xffff0000u);
  x[4]  = __uint_as_float(d1.x << 16); x[5]  = __uint_as_float(d1.x & 0xffff0000u);
  x[6]  = __uint_as_float(d1.y << 16); x[7]  = __uint_as_float(d1.y & 0xffff0000u);
  x[8]  = __uint_as_float(d2.x << 16); x[9]  = __uint_as_float(d2.x & 0xffff0000u);
  x[10] = __uint_as_float(d2.y << 16); x[11] = __uint_as_float(d2.y & 0xffff0000u);
}

__device__ __forceinline__ float max25(const float c[25]) {
  float m0 = fmaxf(fmaxf(c[0], c[1]), c[2]);
  float m1 = fmaxf(fmaxf(c[3], c[4]), c[5]);
  float m2 = fmaxf(fmaxf(c[6], c[7]), c[8]);
  float m3 = fmaxf(fmaxf(c[9], c[10]), c[11]);
  float m4 = fmaxf(fmaxf(c[12], c[13]), c[14]);
  float m5 = fmaxf(fmaxf(c[15], c[16]), c[17]);
  float m6 = fmaxf(fmaxf(c[18], c[19]), c[20]);
  float m7 = fmaxf(fmaxf(c[21], c[22]), c[23]);
  float n0 = fmaxf(fmaxf(m0, m1), m2);
  float n1 = fmaxf(fmaxf(m3, m4), m5);
  float n2 = fmaxf(fmaxf(m6, m7), c[24]);
  return fmaxf(fmaxf(n0, n1), n2);
}

// argmax over 25, first-index tie-break (jnp semantics) — parallel hist-recompute only
__device__ __forceinline__ void argmax25(const float c[25], float& bv, int& bi) {
  float v[13]; int x[13];
#pragma unroll
  for (int i = 0; i < 12; i++) {
    bool t = c[2 * i + 1] > c[2 * i];
    v[i] = t ? c[2 * i + 1] : c[2 * i];
    x[i] = t ? 2 * i + 1 : 2 * i;
  }
  v[12] = c[24]; x[12] = 24;
  float w[7]; int y[7];
#pragma unroll
  for (int i = 0; i < 6; i++) {
    bool t = v[2 * i + 1] > v[2 * i];
    w[i] = t ? v[2 * i + 1] : v[2 * i];
    y[i] = t ? x[2 * i + 1] : x[2 * i];
  }
  w[6] = v[12]; y[6] = x[12];
  float u[4]; int z[4];
#pragma unroll
  for (int i = 0; i < 3; i++) {
    bool t = w[2 * i + 1] > w[2 * i];
    u[i] = t ? w[2 * i + 1] : w[2 * i];
    z[i] = t ? y[2 * i + 1] : y[2 * i];
  }
  u[3] = w[6]; z[3] = y[6];
  bool t0 = u[1] > u[0]; float a = t0 ? u[1] : u[0]; int ai = t0 ? z[1] : z[0];
  bool t1 = u[3] > u[2]; float b = t1 ? u[3] : u[2]; int bj = t1 ? z[3] : z[2];
  bool t2 = b > a; bv = t2 ? b : a; bi = t2 ? bj : ai;
}

// ---------------- Kernel 1: LN(dec)->bf16 + W transpose->bf16 + softmax(cos_sim) ----------------
__global__ __launch_bounds__(256) void prep_kernel(
    const float* __restrict__ decemb, const float* __restrict__ gamma,
    const float* __restrict__ beta, const float* __restrict__ Wadd,
    const float* __restrict__ cosim,
    ushort* __restrict__ decb, ushort* __restrict__ wtb, float* __restrict__ csp) {
  const int blk = blockIdx.x;
  const int tid = threadIdx.x;
  __shared__ float sa[4], sq[4];
  __shared__ float sem[12800];
  if (blk < 800) {
    const float* in = decemb + (size_t)blk * 768;
    float x0 = in[tid], x1 = in[tid + 256], x2 = in[tid + 512];
    float s = x0 + x1 + x2, q = x0 * x0 + x1 * x1 + x2 * x2;
    float ws_ = wsum(s), wq = wsum(q);
    int w = tid >> 6, ln = tid & 63;
    if (ln == 0) { sa[w] = ws_; sq[w] = wq; }
    __syncthreads();
    float s1 = sa[0] + sa[1] + sa[2] + sa[3];
    float s2 = sq[0] + sq[1] + sq[2] + sq[3];
    float mean = s1 * (1.f / 768.f);
    float rstd = rsqrtf(s2 * (1.f / 768.f) - mean * mean + 1e-5f);
    ushort* o = decb + (size_t)blk * 768;
    o[tid]       = f2bf((x0 - mean) * rstd * gamma[tid]       + beta[tid]);
    o[tid + 256] = f2bf((x1 - mean) * rstd * gamma[tid + 256] + beta[tid + 256]);
    o[tid + 512] = f2bf((x2 - mean) * rstd * gamma[tid + 512] + beta[tid + 512]);
  } else if (blk < 832) {
    int gid = (blk - 800) * 256 + tid;
    for (int e = gid; e < 19200; e += 32 * 256) {
      int d = e / 25, j = e - d * 25;
      wtb[j * 768 + d] = f2bf(Wadd[e]);
    }
  } else {
    const int b = blk - 832;
    const float4* cb4 = (const float4*)(cosim + (size_t)b * 12800);
    float4* em4 = (float4*)sem;
    for (int i = tid; i < 3200; i += 256) em4[i] = cb4[i];
    __syncthreads();
#pragma unroll
    for (int rr = 0; rr < 2; rr++) {
      const int r = tid + (rr << 8);
      float v[25];
#pragma unroll
      for (int k = 0; k < 25; k++) v[k] = sem[r * 25 + k];
      float m01 = v[0];
#pragma unroll
      for (int k = 1; k < 25; k++) m01 = fmaxf(m01, v[k]);
      float s = 0.f;
#pragma unroll
      for (int k = 0; k < 25; k++) { v[k] = __expf(v[k] - m01); s += v[k]; }
      float rinv = __builtin_amdgcn_rcpf(s);
#pragma unroll
      for (int k = 0; k < 25; k++) sem[r * 25 + k] = v[k] * rinv;
    }
    __syncthreads();
    float4* cp4 = (float4*)(csp + (size_t)b * 12800);
    for (int i = tid; i < 3200; i += 256) cp4[i] = em4[i];
  }
}

// ---------------- Kernel 2: prioritized Viterbi VALUE scans (bid<64) + streaming 4r/wave ----------------
__global__ __launch_bounds__(256) void main_kernel(
    const float* __restrict__ bert, const float* __restrict__ oenc,
    const float* __restrict__ cosim, const float* __restrict__ gamma,
    const float* __restrict__ beta, const float* __restrict__ badd,
    const ushort* __restrict__ decb, const ushort* __restrict__ wtb,
    const float* __restrict__ csp, const float* __restrict__ startt,
    const float* __restrict__ endt, const float* __restrict__ trans,
    float* __restrict__ nprob, float* __restrict__ traceF,
    float* __restrict__ traceB, float* __restrict__ out) {
  // union LDS: scans: em 6500 f32 (26000 B); streaming: sdec 38400 B then scatter bufs
  __shared__ ushort sh[19200];
  const int tid = threadIdx.x;
  const int lane = tid & 63;
  const int wid = tid >> 6;
  const int bid = blockIdx.x;

  if (bid < 64) {
    // ======== Viterbi value-only scans at ELEVATED PRIORITY ========
    // Co-resident streaming waves fill our dependency bubbles; setprio(1)
    // gives this wave first claim on issue slots (role-split regime).
    const bool isFwd = bid < 32;
    const int b = isFwd ? bid : bid - 32;
    const int tl = (lane < 25) ? lane : 24;
    float* em = (float*)sh;  // rows 0..259 (fwd) or 252..511 (bwd)
    {
      const float4* src4 = (const float4*)(csp + (size_t)b * 12800 + (isFwd ? 0 : 6300));
      float4* dst4 = (float4*)em;
#pragma unroll
      for (int i = 0; i < 7; i++) {
        int e = tid + (i << 8);
        if (e < 1625) dst4[e] = src4[e];
      }
    }
    __syncthreads();
    if (wid != 0) return;

    __builtin_amdgcn_s_setprio(1);
    if (isFwd) {  // t = 0..256, em row t at em[t*25]
      float* tf = traceF + (size_t)b * 16448;
      float Tc[25];
#pragma unroll
      for (int i = 0; i < 25; i++) Tc[i] = trans[i * 25 + tl];
      float sc = startt[tl] + em[tl];
      tf[lane] = sc;
      float emA = em[25 + tl], emB = em[50 + tl];
      for (int t = 1; t <= 256; t++) {
        float emC = em[(t + 2) * 25 + tl];
        float s[25], c[25];
#pragma unroll
        for (int i = 0; i < 25; i++) s[i] = rlane(sc, i);
#pragma unroll
        for (int i = 0; i < 25; i++) c[i] = s[i] + Tc[i];
        float bv = max25(c);
        sc = bv + emA;
        tf[t * 64 + lane] = sc;  // fire-and-forget
        emA = emB; emB = emC;
      }
    } else {  // t = 511..257, em row t at em[(t-252)*25]
      float* tb = traceB + (size_t)b * 16448;
      float Tr[25];
#pragma unroll
      for (int j = 0; j < 25; j++) Tr[j] = trans[tl * 25 + j];
      float bwd = endt[tl];
      float emA = em[(511 - 252) * 25 + tl], emB = em[(510 - 252) * 25 + tl];
      for (int t = 511; t >= 257; t--) {
        float emC = em[(t - 2 - 252) * 25 + tl];
        tb[(511 - t) * 64 + lane] = bwd;  // suffix(t+1)
        float u = bwd + emA;
        float s[25], c[25];
#pragma unroll
        for (int j = 0; j < 25; j++) s[j] = rlane(u, j);
#pragma unroll
        for (int j = 0; j < 25; j++) c[j] = s[j] + Tr[j];
        float bv = max25(c);
        bwd = bv;
        emA = emB; emB = emC;
      }
      tb[255 * 64 + lane] = bwd;  // suffix(257)
    }
    __builtin_amdgcn_s_setprio(0);
    return;
  }

  // ======== streaming path: 4 rows/wave ========
  if (bid == 64 && tid == 0) out[0] = 0.f;  // loss accumulator (crf adds later)
  const int idx = bid - 64;
  const int swz = (idx & 7) * 128 + (idx >> 3);  // bijective XCD swizzle (1024 = 8x128)
  const int b = swz >> 5;                         // 32 blocks/batch
  const int rowg = b * 512 + ((swz & 31) << 4) + (wid << 2);  // 16 rows/block, 4/wave

  // stage decb[b] -> sh (2400 uint4, guarded)
  {
    const uint4* src = (const uint4*)(decb + (size_t)b * 19200);
    uint4* dst = (uint4*)sh;
#pragma unroll
    for (int i = 0; i < 10; i++) {
      int e = tid + (i << 8);
      if (e < 2400) dst[e] = src[e];
    }
  }
  float g[12], bbv[12];
  ld12(g, gamma, lane);
  ld12(bbv, beta, lane);
  float acc[4][12];
#pragma unroll
  for (int r = 0; r < 4; r++) ld12(acc[r], bert + (size_t)(rowg + r) * 768, lane);
  float cs[4];
#pragma unroll
  for (int r = 0; r < 4; r++)
    cs[r] = (lane < 25) ? cosim[(size_t)(rowg + r) * 25 + lane] : 0.f;
  __syncthreads();

  // Phase A: acc = LN(bert)
#pragma unroll
  for (int r = 0; r < 4; r++) {
    float s = 0.f, q = 0.f;
#pragma unroll
    for (int e = 0; e < 12; e++) { s += acc[r][e]; q += acc[r][e] * acc[r][e]; }
    s = wsum(s); q = wsum(q);
    float mean = s * (1.f / 768.f);
    float rstd = rsqrtf(q * (1.f / 768.f) - mean * mean + 1e-5f);
#pragma unroll
    for (int e = 0; e < 12; e++) acc[r][e] = (acc[r][e] - mean) * rstd * g[e] + bbv[e];
  }

  // Phase B: acc += cos_sim @ dec  (LDS bf16, amortized over 4 rows)
  const char* sd = (const char*)sh;
#pragma unroll 5
  for (int c = 0; c < 25; c++) {
    uint2 d0 = *(const uint2*)(sd + c * 1536 + lane * 8);
    uint2 d1 = *(const uint2*)(sd + c * 1536 + lane * 8 + 512);
    uint2 d2 = *(const uint2*)(sd + c * 1536 + lane * 8 + 1024);
    float dv[12];
    dv[0]  = __uint_as_float(d0.x << 16); dv[1]  = __uint_as_float(d0.x & 0xffff0000u);
    dv[2]  = __uint_as_float(d0.y << 16); dv[3]  = __uint_as_float(d0.y & 0xffff0000u);
    dv[4]  = __uint_as_float(d1.x << 16); dv[5]  = __uint_as_float(d1.x & 0xffff0000u);
    dv[6]  = __uint_as_float(d1.y << 16); dv[7]  = __uint_as_float(d1.y & 0xffff0000u);
    dv[8]  = __uint_as_float(d2.x << 16); dv[9]  = __uint_as_float(d2.x & 0xffff0000u);
    dv[10] = __uint_as_float(d2.y << 16); dv[11] = __uint_as_float(d2.y & 0xffff0000u);
    float f0 = rlane(cs[0], c), f1 = rlane(cs[1], c);
    float f2 = rlane(cs[2], c), f3 = rlane(cs[3], c);
#pragma unroll
    for (int e = 0; e < 12; e++) {
      acc[0][e] = fmaf(f0, dv[e], acc[0][e]);
      acc[1][e] = fmaf(f1, dv[e], acc[1][e]);
      acc[2][e] = fmaf(f2, dv[e], acc[2][e]);
      acc[3][e] = fmaf(f3, dv[e], acc[3][e]);
    }
  }

  // += oenc (sequential; y dies per row)
#pragma unroll
  for (int r = 0; r < 4; r++) {
    float y[12];
    ld12(y, oenc + (size_t)(rowg + r) * 768, lane);
#pragma unroll
    for (int e = 0; e < 12; e++) acc[r][e] += y[e];
  }

  // Phase C: acc = relu(LN(acc))
#pragma unroll
  for (int r = 0; r < 4; r++) {
    float s = 0.f, q = 0.f;
#pragma unroll
    for (int e = 0; e < 12; e++) { s += acc[r][e]; q += acc[r][e] * acc[r][e]; }
    s = wsum(s); q = wsum(q);
    float mean = s * (1.f / 768.f);
    float rstd = rsqrtf(q * (1.f / 768.f) - mean * mean + 1e-5f);
#pragma unroll
    for (int e = 0; e < 12; e++)
      acc[r][e] = fmaxf((acc[r][e] - mean) * rstd * g[e] + bbv[e], 0.f);
  }

  __syncthreads();  // done reading sdec -> reuse sh as scatter scratch

  // Phase D: two 2-row passes through the same wave-private scatter buffers
  ushort* scw0 = sh + wid * 3400;
  ushort* scw1 = scw0 + 1700;
  float bav = (lane < 25) ? badd[lane] : 0.f;
  const int jj = (lane < 25) ? lane : 24;
#pragma unroll
  for (int h = 0; h < 2; h++) {
    const int r0 = 2 * h, r1 = 2 * h + 1;
#pragma unroll 5
    for (int j = 0; j < 25; j++) {
      float wv[12];
      ld12bf(wv, wtb + j * 768, lane);
      float p0 = 0.f, p1 = 0.f;
#pragma unroll
      for (int e = 0; e < 12; e++) {
        p0 = fmaf(acc[r0][e], wv[e], p0);
        p1 = fmaf(acc[r1][e], wv[e], p1);
      }
      scw0[j * 68 + lane] = f2bf(p0);
      scw1[j * 68 + lane] = f2bf(p1);
    }
#pragma unroll
    for (int r = 0; r < 2; r++) {
      const ushort* scw = (r == 0) ? scw0 : scw1;
      float lg = bav;
#pragma unroll
      for (int i = 0; i < 16; i++) {
        uint2 u = *(const uint2*)(scw + jj * 68 + i * 4);
        lg += __uint_as_float(u.x << 16);
        lg += __uint_as_float(u.x & 0xffff0000u);
        lg += __uint_as_float(u.y << 16);
        lg += __uint_as_float(u.y & 0xffff0000u);
      }
      float v = (lane < 25) ? lg : NEGINF;
      float m = rfl(lg);  // stability offset cancels analytically
      float e = __expf(v - m);
      float s = wsum(e);
      if (lane < 25)
        nprob[(size_t)(rowg + r0 + r) * 25 + lane] = e * __builtin_amdgcn_rcpf(s);
    }
  }
}

// ---------------- Kernel 3: CRF NLL, linear domain (32 blocks) ----------------
__global__ __launch_bounds__(256) void crf_kernel(
    const float* __restrict__ nprob, const int* __restrict__ labels,
    const float* __restrict__ startt, const float* __restrict__ endt,
    const float* __restrict__ trans, float* __restrict__ out) {
  const int tid = threadIdx.x, lane = tid & 63, wid = tid >> 6;
  const int b = blockIdx.x;
  const int tl = (lane < 25) ? lane : 24;
  __shared__ float fp[32], fq[32], snum[1];
  __shared__ int sKf[1], sKb[1];
  const float* np = nprob + (size_t)b * 12800;

  if (wid == 0) {
    float Mc[25];
#pragma unroll
    for (int i = 0; i < 25; i++) Mc[i] = __expf(trans[i * 25 + tl]);
    float p = (lane < 25) ? __expf(startt[lane]) * np[lane] : 0.f;
    float eA = np[25 + tl], eB = np[50 + tl];
    int K = 0;
    for (int t = 1; t <= 256; t++) {
      float eC = np[(t + 2) * 25 + tl];
      float s[25];
#pragma unroll
      for (int i = 0; i < 25; i++) s[i] = rlane(p, i);
      float a0 = 0, a1 = 0, a2 = 0, a3 = 0, a4 = 0;
#pragma unroll
      for (int i = 0; i < 25; i += 5) {
        a0 = fmaf(s[i + 0], Mc[i + 0], a0);
        a1 = fmaf(s[i + 1], Mc[i + 1], a1);
        a2 = fmaf(s[i + 2], Mc[i + 2], a2);
        a3 = fmaf(s[i + 3], Mc[i + 3], a3);
        a4 = fmaf(s[i + 4], Mc[i + 4], a4);
      }
      float acc = ((a0 + a1) + (a2 + a3)) + a4;
      if ((t & 7) == 0) {
        unsigned mu = 0;
#pragma unroll
        for (int i = 0; i < 25; i++) {
          unsigned ub = __float_as_uint(s[i]);
          mu = (ub > mu) ? ub : mu;
        }
        int e8 = (int)((mu >> 23) & 0xFF);
        acc *= __uint_as_float((unsigned)(254 - e8) << 23);
        K += 127 - e8;
      }
      p = (lane < 25) ? acc * eA : 0.f;
      eA = eB; eB = eC;
    }
    if (lane < 25) fp[lane] = p;
    if (lane == 0) sKf[0] = K;
  } else if (wid == 1) {
    float MrE[25];
#pragma unroll
    for (int j = 0; j < 25; j++) MrE[j] = __expf(trans[tl * 25 + j]);
    float q = (lane < 25) ? __expf(endt[lane]) : 0.f;
    float eA = np[511 * 25 + tl], eB = np[510 * 25 + tl];
    int K = 0;
    for (int t = 511; t >= 257; t--) {
      float eC = np[(t - 2) * 25 + tl];
      float u = q * eA;
      float s[25];
#pragma unroll
      for (int j = 0; j < 25; j++) s[j] = rlane(u, j);
      float a0 = 0, a1 = 0, a2 = 0, a3 = 0, a4 = 0;
#pragma unroll
      for (int j = 0; j < 25; j += 5) {
        a0 = fmaf(s[j + 0], MrE[j + 0], a0);
        a1 = fmaf(s[j + 1], MrE[j + 1], a1);
        a2 = fmaf(s[j + 2], MrE[j + 2], a2);
        a3 = fmaf(s[j + 3], MrE[j + 3], a3);
        a4 = fmaf(s[j + 4], MrE[j + 4], a4);
      }
      float acc = ((a0 + a1) + (a2 + a3)) + a4;
      if ((t & 7) == 0) {
        unsigned mu = 0;
#pragma unroll
        for (int j = 0; j < 25; j++) {
          unsigned ub = __float_as_uint(s[j]);
          mu = (ub > mu) ? ub : mu;
        }
        int e8 = (int)((mu >> 23) & 0xFF);
        acc *= __uint_as_float((unsigned)(254 - e8) << 23);
        K += 127 - e8;
      }
      q = (lane < 25) ? acc : 0.f;
      eA = eB; eB = eC;
    }
    if (lane < 25) fq[lane] = q;
    if (lane == 0) sKb[0] = K;
  } else if (wid == 2) {
    float a = 0.f;
    const int* lb = labels + b * 512;
    for (int t = lane; t < 512; t += 64) a += __logf(np[t * 25 + lb[t]]);
    for (int t = lane; t < 511; t += 64) a += trans[lb[t] * 25 + lb[t + 1]];
    a = wsum(a);
    if (lane == 0) snum[0] = a + startt[lb[0]] + endt[lb[511]];
  }
  __syncthreads();
  if (wid == 0) {
    float z = (lane < 25) ? fp[lane] * fq[lane] : 0.f;
    z = wsum(z);
    float logZ = __logf(z) - (float)(sKf[0] + sKb[0]) * 0.6931471805599453f;
    float llh = snum[0] - logZ;
    if (lane == 0) atomicAdd(out, -llh * (1.f / 32.f));
  }
}

// ---------------- Kernel 4: Viterbi hist recompute (parallel over t) + backtrace ----------------
__global__ __launch_bounds__(256) void scan2_kernel(
    const float* __restrict__ csp, const float* __restrict__ traceF,
    const float* __restrict__ traceB, const float* __restrict__ trans,
    float* __restrict__ out) {
  const int tid = threadIdx.x, lane = tid & 63, wid = tid >> 6;
  const int vb = blockIdx.x;  // 0..63
  const int b = vb & 31;
  const bool isFwd = vb < 32;
  const int tl = (lane < 25) ? lane : 24;
  __shared__ __align__(16) unsigned char hist[13568];  // [513][26] bytes
  const float* tf = traceF + (size_t)b * 16448;
  const float* tb = traceB + (size_t)b * 16448;

  if (isFwd) {
    float Tc[25];
#pragma unroll
    for (int i = 0; i < 25; i++) Tc[i] = trans[i * 25 + tl];
    int t0 = 1 + (wid << 6);
    float vA = tf[(t0 - 1) * 64 + tl];
    for (int n = 0; n < 64; n++) {
      int t = t0 + n;
      float vB = (n < 63) ? tf[t * 64 + tl] : 0.f;
      float s[25], c[25];
#pragma unroll
      for (int i = 0; i < 25; i++) s[i] = rlane(vA, i);
#pragma unroll
      for (int i = 0; i < 25; i++) c[i] = s[i] + Tc[i];
      float bv; int bi;
      argmax25(c, bv, bi);
      if (lane < 25) hist[t * 26 + lane] = (unsigned char)bi;
      vA = vB;
    }
  } else {
    float Tr[25];
#pragma unroll
    for (int j = 0; j < 25; j++) Tr[j] = trans[tl * 25 + j];
    const float* cb = csp + (size_t)b * 12800;
    int t0 = 257 + (wid << 6);
    float tA = (t0 <= 511) ? tb[(511 - t0) * 64 + tl] : 0.f;
    float eA = (t0 <= 511) ? cb[t0 * 25 + tl] : 0.f;
    for (int n = 0; n < 64; n++) {
      int t = t0 + n;
      if (t > 511) break;
      float tBn = (t < 511) ? tb[(511 - t - 1) * 64 + tl] : 0.f;
      float eBn = (t < 511) ? cb[(t + 1) * 25 + tl] : 0.f;
      float u = tA + eA;
      float s[25], c[25];
#pragma unroll
      for (int j = 0; j < 25; j++) s[j] = rlane(u, j);
#pragma unroll
      for (int j = 0; j < 25; j++) c[j] = s[j] + Tr[j];
      float bv; int bj;
      argmax25(c, bv, bj);
      if (lane < 25) hist[t * 26 + lane] = (unsigned char)bj;
      tA = tBn; eA = eBn;
    }
  }
  __syncthreads();
  if (wid == 0) {
    float fv = (lane < 25) ? tf[256 * 64 + lane] + tb[255 * 64 + lane] : NEGINF;
    int idx = lane;
#pragma unroll
    for (int m = 32; m >= 1; m >>= 1) {
      float ov = __shfl_xor(fv, m); int oi = __shfl_xor(idx, m);
      if (ov > fv || (ov == fv && oi < idx)) { fv = ov; idx = oi; }
    }
    int cur = idx;  // uniform
    float* path = out + 1 + (size_t)b * 512;
    if (isFwd) {
      if (lane == 0) path[256] = (float)cur;
      int h = (lane < 25) ? hist[256 * 26 + lane] : 0;
      for (int t = 256; t >= 1; t--) {
        int hn = (t > 1 && lane < 25) ? hist[(t - 1) * 26 + lane] : 0;
        int prev = __builtin_amdgcn_readlane(h, cur);
        if (lane == 0) path[t - 1] = (float)prev;
        cur = prev; h = hn;
      }
    } else {
      int h = (lane < 25) ? hist[257 * 26 + lane] : 0;
      for (int t = 257; t <= 511; t++) {
        int hn = (t < 511 && lane < 25) ? hist[(t + 1) * 26 + lane] : 0;
        int nx = __builtin_amdgcn_readlane(h, cur);
        if (lane == 0) path[t] = (float)nx;
        cur = nx; h = hn;
      }
    }
  }
}

extern "C" void kernel_launch(void* const* d_in, const int* in_sizes, int n_in,
                              void* d_out, int out_size, void* d_ws, size_t ws_size,
                              hipStream_t stream) {
  (void)in_sizes; (void)n_in; (void)out_size; (void)ws_size;
  const float* bert   = (const float*)d_in[0];
  const float* oenc   = (const float*)d_in[1];
  const float* cosim  = (const float*)d_in[2];
  const float* decemb = (const float*)d_in[3];
  const int*   labels = (const int*)d_in[4];
  const float* gamma  = (const float*)d_in[5];
  const float* beta   = (const float*)d_in[6];
  const float* Wadd   = (const float*)d_in[7];
  const float* badd   = (const float*)d_in[8];
  const float* startt = (const float*)d_in[9];
  const float* endt   = (const float*)d_in[10];
  const float* trans  = (const float*)d_in[11];
  float* out = (float*)d_out;
  char*  wsb = (char*)d_ws;
  ushort* decb   = (ushort*)wsb;                 // [0, 1228800)
  ushort* wtb    = (ushort*)(wsb + 1228800);     // [1228800, 1267200)
  float*  nprob  = (float*)(wsb + 1305600);      // [1305600, 2944000)
  float*  csp    = (float*)(wsb + 2944000);      // [2944000, 4582400)
  float*  traceF = (float*)(wsb + 4582400);      // [4582400, 6687744)
  float*  traceB = (float*)(wsb + 6687744);      // [6687744, 8793088)

  prep_kernel<<<864, 256, 0, stream>>>(decemb, gamma, beta, Wadd, cosim, decb, wtb, csp);
  main_kernel<<<1088, 256, 0, stream>>>(bert, oenc, cosim, gamma, beta, badd, decb, wtb,
                                        csp, startt, endt, trans, nprob, traceF, traceB, out);
  crf_kernel<<<32, 256, 0, stream>>>(nprob, labels, startt, endt, trans, out);
  scan2_kernel<<<64, 256, 0, stream>>>(csp, traceF, traceB, trans, out);
}

// Round 16
// 108.882 us; speedup vs baseline: 1.3280x; 1.3280x over previous
//
#include <hip/hip_runtime.h>
#include <hip/hip_bf16.h>

// NerTr fused pipeline for MI355X (gfx950).  B=32, S=512, D=768, C=25.
// ws layout (bytes):
//   decb  (bf16 32*25*768)    [0, 1228800)
//   wtb   (bf16 25*768)       [1228800, 1267200)
//   nprob (f32 32*512*25)     [1305600, 2944000)
//   csp   (f32 32*512*25)     [2944000, 4582400)
//   traceF(f32 32*16448)      [4582400, 6687744)   viterbi fwd states, stride 64/step
//   traceB(f32 32*16448)      [6687744, 8793088)   viterbi bwd suffix states, stride 64
// out: [0]=loss (f32), [1 + b*512 + t] = viterbi tag (as f32).

#define NEGINF (-1e30f)

__device__ __forceinline__ float rlane(float x, int i) {
  return __int_as_float(__builtin_amdgcn_readlane(__float_as_int(x), i));
}
__device__ __forceinline__ float rfl(float x) {
  return __int_as_float(__builtin_amdgcn_readfirstlane(__float_as_int(x)));
}
template <int CTRL, int RMASK>
__device__ __forceinline__ float dppAdd(float x) {
  return x + __int_as_float(__builtin_amdgcn_update_dpp(
                 0, __float_as_int(x), CTRL, RMASK, 0xF, true));
}
__device__ __forceinline__ float wsum(float v) {
  v = dppAdd<0x111, 0xF>(v);
  v = dppAdd<0x112, 0xF>(v);
  v = dppAdd<0x114, 0xF>(v);
  v = dppAdd<0x118, 0xF>(v);
  v = dppAdd<0x142, 0xA>(v);
  v = dppAdd<0x143, 0xC>(v);
  return rlane(v, 63);
}
__device__ __forceinline__ ushort f2bf(float x) {
  __hip_bfloat16 h = __float2bfloat16(x);
  return *reinterpret_cast<ushort*>(&h);
}
__device__ __forceinline__ void ld12(float* x, const float* p, int lane) {
#pragma unroll
  for (int k = 0; k < 3; k++) {
    float4 v = *(const float4*)(p + (lane + (k << 6)) * 4);
    x[4 * k + 0] = v.x; x[4 * k + 1] = v.y; x[4 * k + 2] = v.z; x[4 * k + 3] = v.w;
  }
}
__device__ __forceinline__ void ld12bf(float* x, const ushort* row, int lane) {
  uint2 d0 = *(const uint2*)((const char*)row + lane * 8);
  uint2 d1 = *(const uint2*)((const char*)row + lane * 8 + 512);
  uint2 d2 = *(const uint2*)((const char*)row + lane * 8 + 1024);
  x[0]  = __uint_as_float(d0.x << 16); x[1]  = __uint_as_float(d0.x & 0xffff0000u);
  x[2]  = __uint_as_float(d0.y << 16); x[3]  = __uint_as_float(d0.y & 0xffff0000u);
  x[4]  = __uint_as_float(d1.x << 16); x[5]  = __uint_as_float(d1.x & 0xffff0000u);
  x[6]  = __uint_as_float(d1.y << 16); x[7]  = __uint_as_float(d1.y & 0xffff0000u);
  x[8]  = __uint_as_float(d2.x << 16); x[9]  = __uint_as_float(d2.x & 0xffff0000u);
  x[10] = __uint_as_float(d2.y << 16); x[11] = __uint_as_float(d2.y & 0xffff0000u);
}

__device__ __forceinline__ float max25(const float c[25]) {
  float m0 = fmaxf(fmaxf(c[0], c[1]), c[2]);
  float m1 = fmaxf(fmaxf(c[3], c[4]), c[5]);
  float m2 = fmaxf(fmaxf(c[6], c[7]), c[8]);
  float m3 = fmaxf(fmaxf(c[9], c[10]), c[11]);
  float m4 = fmaxf(fmaxf(c[12], c[13]), c[14]);
  float m5 = fmaxf(fmaxf(c[15], c[16]), c[17]);
  float m6 = fmaxf(fmaxf(c[18], c[19]), c[20]);
  float m7 = fmaxf(fmaxf(c[21], c[22]), c[23]);
  float n0 = fmaxf(fmaxf(m0, m1), m2);
  float n1 = fmaxf(fmaxf(m3, m4), m5);
  float n2 = fmaxf(fmaxf(m6, m7), c[24]);
  return fmaxf(fmaxf(n0, n1), n2);
}

// argmax over 25, first-index tie-break (jnp semantics) — parallel hist-recompute only
__device__ __forceinline__ void argmax25(const float c[25], float& bv, int& bi) {
  float v[13]; int x[13];
#pragma unroll
  for (int i = 0; i < 12; i++) {
    bool t = c[2 * i + 1] > c[2 * i];
    v[i] = t ? c[2 * i + 1] : c[2 * i];
    x[i] = t ? 2 * i + 1 : 2 * i;
  }
  v[12] = c[24]; x[12] = 24;
  float w[7]; int y[7];
#pragma unroll
  for (int i = 0; i < 6; i++) {
    bool t = v[2 * i + 1] > v[2 * i];
    w[i] = t ? v[2 * i + 1] : v[2 * i];
    y[i] = t ? x[2 * i + 1] : x[2 * i];
  }
  w[6] = v[12]; y[6] = x[12];
  float u[4]; int z[4];
#pragma unroll
  for (int i = 0; i < 3; i++) {
    bool t = w[2 * i + 1] > w[2 * i];
    u[i] = t ? w[2 * i + 1] : w[2 * i];
    z[i] = t ? y[2 * i + 1] : y[2 * i];
  }
  u[3] = w[6]; z[3] = y[6];
  bool t0 = u[1] > u[0]; float a = t0 ? u[1] : u[0]; int ai = t0 ? z[1] : z[0];
  bool t1 = u[3] > u[2]; float b = t1 ? u[3] : u[2]; int bj = t1 ? z[3] : z[2];
  bool t2 = b > a; bv = t2 ? b : a; bi = t2 ? bj : ai;
}

// ---------------- Kernel 1: LN(dec)->bf16 + W transpose->bf16 + softmax(cos_sim) ----------------
__global__ __launch_bounds__(256) void prep_kernel(
    const float* __restrict__ decemb, const float* __restrict__ gamma,
    const float* __restrict__ beta, const float* __restrict__ Wadd,
    const float* __restrict__ cosim,
    ushort* __restrict__ decb, ushort* __restrict__ wtb, float* __restrict__ csp) {
  const int blk = blockIdx.x;
  const int tid = threadIdx.x;
  __shared__ float sa[4], sq[4];
  __shared__ float sem[12800];
  if (blk < 800) {
    const float* in = decemb + (size_t)blk * 768;
    float x0 = in[tid], x1 = in[tid + 256], x2 = in[tid + 512];
    float s = x0 + x1 + x2, q = x0 * x0 + x1 * x1 + x2 * x2;
    float ws_ = wsum(s), wq = wsum(q);
    int w = tid >> 6, ln = tid & 63;
    if (ln == 0) { sa[w] = ws_; sq[w] = wq; }
    __syncthreads();
    float s1 = sa[0] + sa[1] + sa[2] + sa[3];
    float s2 = sq[0] + sq[1] + sq[2] + sq[3];
    float mean = s1 * (1.f / 768.f);
    float rstd = rsqrtf(s2 * (1.f / 768.f) - mean * mean + 1e-5f);
    ushort* o = decb + (size_t)blk * 768;
    o[tid]       = f2bf((x0 - mean) * rstd * gamma[tid]       + beta[tid]);
    o[tid + 256] = f2bf((x1 - mean) * rstd * gamma[tid + 256] + beta[tid + 256]);
    o[tid + 512] = f2bf((x2 - mean) * rstd * gamma[tid + 512] + beta[tid + 512]);
  } else if (blk < 832) {
    int gid = (blk - 800) * 256 + tid;
    for (int e = gid; e < 19200; e += 32 * 256) {
      int d = e / 25, j = e - d * 25;
      wtb[j * 768 + d] = f2bf(Wadd[e]);
    }
  } else {
    const int b = blk - 832;
    const float4* cb4 = (const float4*)(cosim + (size_t)b * 12800);
    float4* em4 = (float4*)sem;
    for (int i = tid; i < 3200; i += 256) em4[i] = cb4[i];
    __syncthreads();
#pragma unroll
    for (int rr = 0; rr < 2; rr++) {
      const int r = tid + (rr << 8);
      float v[25];
#pragma unroll
      for (int k = 0; k < 25; k++) v[k] = sem[r * 25 + k];
      float m01 = v[0];
#pragma unroll
      for (int k = 1; k < 25; k++) m01 = fmaxf(m01, v[k]);
      float s = 0.f;
#pragma unroll
      for (int k = 0; k < 25; k++) { v[k] = __expf(v[k] - m01); s += v[k]; }
      float rinv = __builtin_amdgcn_rcpf(s);
#pragma unroll
      for (int k = 0; k < 25; k++) sem[r * 25 + k] = v[k] * rinv;
    }
    __syncthreads();
    float4* cp4 = (float4*)(csp + (size_t)b * 12800);
    for (int i = tid; i < 3200; i += 256) cp4[i] = em4[i];
  }
}

// ---------------- Kernel 2: prioritized Viterbi VALUE scans (bid<64) + barrier-free streaming ----------------
__global__ __launch_bounds__(256) void main_kernel(
    const float* __restrict__ bert, const float* __restrict__ oenc,
    const float* __restrict__ cosim, const float* __restrict__ gamma,
    const float* __restrict__ beta, const float* __restrict__ badd,
    const ushort* __restrict__ decb, const ushort* __restrict__ wtb,
    const float* __restrict__ csp, const float* __restrict__ startt,
    const float* __restrict__ endt, const float* __restrict__ trans,
    float* __restrict__ nprob, float* __restrict__ traceF,
    float* __restrict__ traceB, float* __restrict__ out) {
  // union LDS (27200 B): scan blocks em 6500 f32 (26000 B); streaming scatter bufs 4x6800 B
  __shared__ ushort sh[13600];
  const int tid = threadIdx.x;
  const int lane = tid & 63;
  const int wid = tid >> 6;
  const int bid = blockIdx.x;

  if (bid < 64) {
    // ======== Viterbi value-only scans at elevated priority ========
    // Role-split: this wave is dependency-bound; co-resident streaming waves
    // are throughput-bound. setprio(1) reclaims issue slots stolen by them.
    const bool isFwd = bid < 32;
    const int b = isFwd ? bid : bid - 32;
    const int tl = (lane < 25) ? lane : 24;
    float* em = (float*)sh;  // rows 0..259 (fwd) or 252..511 (bwd)
    {
      const float4* src4 = (const float4*)(csp + (size_t)b * 12800 + (isFwd ? 0 : 6300));
      float4* dst4 = (float4*)em;
#pragma unroll
      for (int i = 0; i < 7; i++) {
        int e = tid + (i << 8);
        if (e < 1625) dst4[e] = src4[e];
      }
    }
    __syncthreads();
    if (wid != 0) return;

    __builtin_amdgcn_s_setprio(1);
    if (isFwd) {  // t = 0..256, em row t at em[t*25]
      float* tf = traceF + (size_t)b * 16448;
      float Tc[25];
#pragma unroll
      for (int i = 0; i < 25; i++) Tc[i] = trans[i * 25 + tl];
      float sc = startt[tl] + em[tl];
      tf[lane] = sc;
      float emA = em[25 + tl], emB = em[50 + tl];
      for (int t = 1; t <= 256; t++) {
        float emC = em[(t + 2) * 25 + tl];
        float s[25], c[25];
#pragma unroll
        for (int i = 0; i < 25; i++) s[i] = rlane(sc, i);
#pragma unroll
        for (int i = 0; i < 25; i++) c[i] = s[i] + Tc[i];
        float bv = max25(c);
        sc = bv + emA;
        tf[t * 64 + lane] = sc;  // fire-and-forget
        emA = emB; emB = emC;
      }
    } else {  // t = 511..257, em row t at em[(t-252)*25]
      float* tb = traceB + (size_t)b * 16448;
      float Tr[25];
#pragma unroll
      for (int j = 0; j < 25; j++) Tr[j] = trans[tl * 25 + j];
      float bwd = endt[tl];
      float emA = em[(511 - 252) * 25 + tl], emB = em[(510 - 252) * 25 + tl];
      for (int t = 511; t >= 257; t--) {
        float emC = em[(t - 2 - 252) * 25 + tl];
        tb[(511 - t) * 64 + lane] = bwd;  // suffix(t+1)
        float u = bwd + emA;
        float s[25], c[25];
#pragma unroll
        for (int j = 0; j < 25; j++) s[j] = rlane(u, j);
#pragma unroll
        for (int j = 0; j < 25; j++) c[j] = s[j] + Tr[j];
        float bv = max25(c);
        bwd = bv;
        emA = emB; emB = emC;
      }
      tb[255 * 64 + lane] = bwd;  // suffix(257)
    }
    __builtin_amdgcn_s_setprio(0);
    return;
  }

  // ======== streaming path: 2 rows/wave, NO barriers, global bf16 dec ========
  if (bid == 64 && tid == 0) out[0] = 0.f;  // loss accumulator (tail adds later)
  const int idx = bid - 64;
  const int swz = (idx & 7) * 256 + (idx >> 3);  // bijective XCD swizzle (2048 = 8x256)
  const int b = swz >> 6;
  const int rowg = b * 512 + ((swz & 63) << 3) + (wid << 1);

  float g[12], bbv[12];
  ld12(g, gamma, lane);
  ld12(bbv, beta, lane);
  float acc[2][12];
  ld12(acc[0], bert + (size_t)(rowg + 0) * 768, lane);
  ld12(acc[1], bert + (size_t)(rowg + 1) * 768, lane);
  float cs0 = (lane < 25) ? cosim[(size_t)(rowg + 0) * 25 + lane] : 0.f;
  float cs1 = (lane < 25) ? cosim[(size_t)(rowg + 1) * 25 + lane] : 0.f;

  // Phase A: acc = LN(bert)
#pragma unroll
  for (int r = 0; r < 2; r++) {
    float s = 0.f, q = 0.f;
#pragma unroll
    for (int e = 0; e < 12; e++) { s += acc[r][e]; q += acc[r][e] * acc[r][e]; }
    s = wsum(s); q = wsum(q);
    float mean = s * (1.f / 768.f);
    float rstd = rsqrtf(q * (1.f / 768.f) - mean * mean + 1e-5f);
#pragma unroll
    for (int e = 0; e < 12; e++) acc[r][e] = (acc[r][e] - mean) * rstd * g[e] + bbv[e];
  }

  // Phase B: acc += cos_sim @ dec  (bf16 dec from global/L2, unroll-5 pipelined)
  const ushort* db = decb + (size_t)b * 19200;
#pragma unroll 5
  for (int c = 0; c < 25; c++) {
    float dv[12];
    ld12bf(dv, db + c * 768, lane);
    float f0 = rlane(cs0, c), f1 = rlane(cs1, c);
#pragma unroll
    for (int e = 0; e < 12; e++) {
      acc[0][e] = fmaf(f0, dv[e], acc[0][e]);
      acc[1][e] = fmaf(f1, dv[e], acc[1][e]);
    }
  }

  // += oenc
#pragma unroll
  for (int r = 0; r < 2; r++) {
    float y[12];
    ld12(y, oenc + (size_t)(rowg + r) * 768, lane);
#pragma unroll
    for (int e = 0; e < 12; e++) acc[r][e] += y[e];
  }

  // Phase C: acc = relu(LN(acc))
#pragma unroll
  for (int r = 0; r < 2; r++) {
    float s = 0.f, q = 0.f;
#pragma unroll
    for (int e = 0; e < 12; e++) { s += acc[r][e]; q += acc[r][e] * acc[r][e]; }
    s = wsum(s); q = wsum(q);
    float mean = s * (1.f / 768.f);
    float rstd = rsqrtf(q * (1.f / 768.f) - mean * mean + 1e-5f);
#pragma unroll
    for (int e = 0; e < 12; e++)
      acc[r][e] = fmaxf((acc[r][e] - mean) * rstd * g[e] + bbv[e], 0.f);
  }

  // Phase D: logits, bf16 wt, unroll-5 pipelined, wave-private LDS scatter (no barriers)
  ushort* scw0 = sh + wid * 3400;
  ushort* scw1 = scw0 + 1700;
#pragma unroll 5
  for (int j = 0; j < 25; j++) {
    float wv[12];
    ld12bf(wv, wtb + j * 768, lane);
    float p0 = 0.f, p1 = 0.f;
#pragma unroll
    for (int e = 0; e < 12; e++) {
      p0 = fmaf(acc[0][e], wv[e], p0);
      p1 = fmaf(acc[1][e], wv[e], p1);
    }
    scw0[j * 68 + lane] = f2bf(p0);
    scw1[j * 68 + lane] = f2bf(p1);
  }
  float bav = (lane < 25) ? badd[lane] : 0.f;
  const int jj = (lane < 25) ? lane : 24;
#pragma unroll
  for (int r = 0; r < 2; r++) {
    const ushort* scw = (r == 0) ? scw0 : scw1;
    float lg = bav;
#pragma unroll
    for (int i = 0; i < 16; i++) {
      uint2 u = *(const uint2*)(scw + jj * 68 + i * 4);
      lg += __uint_as_float(u.x << 16);
      lg += __uint_as_float(u.x & 0xffff0000u);
      lg += __uint_as_float(u.y << 16);
      lg += __uint_as_float(u.y & 0xffff0000u);
    }
    float v = (lane < 25) ? lg : NEGINF;
    float m = rfl(lg);  // stability offset cancels analytically
    float e = __expf(v - m);
    float s = wsum(e);
    if (lane < 25) nprob[(size_t)(rowg + r) * 25 + lane] = e * __builtin_amdgcn_rcpf(s);
  }
}

// ---------------- Kernel 3: CRF linear (0..31) || Viterbi finish (32..95) ----------------
__global__ __launch_bounds__(256) void scan_kernel(
    const float* __restrict__ nprob, const float* __restrict__ csp,
    const float* __restrict__ traceF, const float* __restrict__ traceB,
    const int* __restrict__ labels, const float* __restrict__ startt,
    const float* __restrict__ endt, const float* __restrict__ trans,
    float* __restrict__ out) {
  const int tid = threadIdx.x, lane = tid & 63, wid = tid >> 6;
  const int blk = blockIdx.x;
  const int tl = (lane < 25) ? lane : 24;
  __shared__ __align__(16) unsigned char shraw[13568];

  if (blk < 32) {
    // ======== CRF NLL, linear-domain scans with pow2 renorm ========
    const int b = blk;
    const float* np = nprob + (size_t)b * 12800;
    float* fp = (float*)shraw;
    float* fq = fp + 32;
    float* snum = fq + 32;
    int* sKf = (int*)(snum + 1);
    int* sKb = sKf + 1;
    if (wid == 0) {
      float Mc[25];
#pragma unroll
      for (int i = 0; i < 25; i++) Mc[i] = __expf(trans[i * 25 + tl]);
      float p = (lane < 25) ? __expf(startt[lane]) * np[lane] : 0.f;
      float eA = np[25 + tl], eB = np[50 + tl];
      int K = 0;
      for (int t = 1; t <= 256; t++) {
        float eC = np[(t + 2) * 25 + tl];
        float s[25];
#pragma unroll
        for (int i = 0; i < 25; i++) s[i] = rlane(p, i);
        float a0 = 0, a1 = 0, a2 = 0, a3 = 0, a4 = 0;
#pragma unroll
        for (int i = 0; i < 25; i += 5) {
          a0 = fmaf(s[i + 0], Mc[i + 0], a0);
          a1 = fmaf(s[i + 1], Mc[i + 1], a1);
          a2 = fmaf(s[i + 2], Mc[i + 2], a2);
          a3 = fmaf(s[i + 3], Mc[i + 3], a3);
          a4 = fmaf(s[i + 4], Mc[i + 4], a4);
        }
        float acc = ((a0 + a1) + (a2 + a3)) + a4;
        if ((t & 7) == 0) {
          unsigned mu = 0;
#pragma unroll
          for (int i = 0; i < 25; i++) {
            unsigned ub = __float_as_uint(s[i]);
            mu = (ub > mu) ? ub : mu;
          }
          int e8 = (int)((mu >> 23) & 0xFF);
          acc *= __uint_as_float((unsigned)(254 - e8) << 23);
          K += 127 - e8;
        }
        p = (lane < 25) ? acc * eA : 0.f;
        eA = eB; eB = eC;
      }
      if (lane < 25) fp[lane] = p;
      if (lane == 0) *sKf = K;
    } else if (wid == 1) {
      float MrE[25];
#pragma unroll
      for (int j = 0; j < 25; j++) MrE[j] = __expf(trans[tl * 25 + j]);
      float q = (lane < 25) ? __expf(endt[lane]) : 0.f;
      float eA = np[511 * 25 + tl], eB = np[510 * 25 + tl];
      int K = 0;
      for (int t = 511; t >= 257; t--) {
        float eC = np[(t - 2) * 25 + tl];
        float u = q * eA;
        float s[25];
#pragma unroll
        for (int j = 0; j < 25; j++) s[j] = rlane(u, j);
        float a0 = 0, a1 = 0, a2 = 0, a3 = 0, a4 = 0;
#pragma unroll
        for (int j = 0; j < 25; j += 5) {
          a0 = fmaf(s[j + 0], MrE[j + 0], a0);
          a1 = fmaf(s[j + 1], MrE[j + 1], a1);
          a2 = fmaf(s[j + 2], MrE[j + 2], a2);
          a3 = fmaf(s[j + 3], MrE[j + 3], a3);
          a4 = fmaf(s[j + 4], MrE[j + 4], a4);
        }
        float acc = ((a0 + a1) + (a2 + a3)) + a4;
        if ((t & 7) == 0) {
          unsigned mu = 0;
#pragma unroll
          for (int j = 0; j < 25; j++) {
            unsigned ub = __float_as_uint(s[j]);
            mu = (ub > mu) ? ub : mu;
          }
          int e8 = (int)((mu >> 23) & 0xFF);
          acc *= __uint_as_float((unsigned)(254 - e8) << 23);
          K += 127 - e8;
        }
        q = (lane < 25) ? acc : 0.f;
        eA = eB; eB = eC;
      }
      if (lane < 25) fq[lane] = q;
      if (lane == 0) *sKb = K;
    } else if (wid == 2) {
      float a = 0.f;
      const int* lb = labels + b * 512;
      for (int t = lane; t < 512; t += 64) a += __logf(np[t * 25 + lb[t]]);
      for (int t = lane; t < 511; t += 64) a += trans[lb[t] * 25 + lb[t + 1]];
      a = wsum(a);
      if (lane == 0) *snum = a + startt[lb[0]] + endt[lb[511]];
    }
    __syncthreads();
    if (wid == 0) {
      float z = (lane < 25) ? fp[lane] * fq[lane] : 0.f;
      z = wsum(z);
      float logZ = __logf(z) - (float)(*sKf + *sKb) * 0.6931471805599453f;
      float llh = *snum - logZ;
      if (lane == 0) atomicAdd(out, -llh * (1.f / 32.f));
    }
    return;
  }

  // ======== Viterbi finish: parallel hist recompute + backtrace ========
  const int vb = blk - 32;          // 0..63
  const int b = vb & 31;
  const bool isFwd = vb < 32;
  unsigned char* hist = shraw;      // [513][26] bytes
  const float* tf = traceF + (size_t)b * 16448;
  const float* tb = traceB + (size_t)b * 16448;

  if (isFwd) {
    float Tc[25];
#pragma unroll
    for (int i = 0; i < 25; i++) Tc[i] = trans[i * 25 + tl];
    int t0 = 1 + (wid << 6);
    float vA = tf[(t0 - 1) * 64 + tl];
    for (int n = 0; n < 64; n++) {
      int t = t0 + n;
      float vB = (n < 63) ? tf[t * 64 + tl] : 0.f;
      float s[25], c[25];
#pragma unroll
      for (int i = 0; i < 25; i++) s[i] = rlane(vA, i);
#pragma unroll
      for (int i = 0; i < 25; i++) c[i] = s[i] + Tc[i];
      float bv; int bi;
      argmax25(c, bv, bi);
      if (lane < 25) hist[t * 26 + lane] = (unsigned char)bi;
      vA = vB;
    }
  } else {
    float Tr[25];
#pragma unroll
    for (int j = 0; j < 25; j++) Tr[j] = trans[tl * 25 + j];
    const float* cb = csp + (size_t)b * 12800;
    int t0 = 257 + (wid << 6);
    float tA = (t0 <= 511) ? tb[(511 - t0) * 64 + tl] : 0.f;
    float eA = (t0 <= 511) ? cb[t0 * 25 + tl] : 0.f;
    for (int n = 0; n < 64; n++) {
      int t = t0 + n;
      if (t > 511) break;
      float tBn = (t < 511) ? tb[(511 - t - 1) * 64 + tl] : 0.f;
      float eBn = (t < 511) ? cb[(t + 1) * 25 + tl] : 0.f;
      float u = tA + eA;
      float s[25], c[25];
#pragma unroll
      for (int j = 0; j < 25; j++) s[j] = rlane(u, j);
#pragma unroll
      for (int j = 0; j < 25; j++) c[j] = s[j] + Tr[j];
      float bv; int bj;
      argmax25(c, bv, bj);
      if (lane < 25) hist[t * 26 + lane] = (unsigned char)bj;
      tA = tBn; eA = eBn;
    }
  }
  __syncthreads();
  if (wid == 0) {
    float fv = (lane < 25) ? tf[256 * 64 + lane] + tb[255 * 64 + lane] : NEGINF;
    int idx = lane;
#pragma unroll
    for (int m = 32; m >= 1; m >>= 1) {
      float ov = __shfl_xor(fv, m); int oi = __shfl_xor(idx, m);
      if (ov > fv || (ov == fv && oi < idx)) { fv = ov; idx = oi; }
    }
    int cur = idx;  // uniform
    float* path = out + 1 + (size_t)b * 512;
    if (isFwd) {
      if (lane == 0) path[256] = (float)cur;
      int h = (lane < 25) ? hist[256 * 26 + lane] : 0;
      for (int t = 256; t >= 1; t--) {
        int hn = (t > 1 && lane < 25) ? hist[(t - 1) * 26 + lane] : 0;
        int prev = __builtin_amdgcn_readlane(h, cur);
        if (lane == 0) path[t - 1] = (float)prev;
        cur = prev; h = hn;
      }
    } else {
      int h = (lane < 25) ? hist[257 * 26 + lane] : 0;
      for (int t = 257; t <= 511; t++) {
        int hn = (t < 511 && lane < 25) ? hist[(t + 1) * 26 + lane] : 0;
        int nx = __builtin_amdgcn_readlane(h, cur);
        if (lane == 0) path[t] = (float)nx;
        cur = nx; h = hn;
      }
    }
  }
}

extern "C" void kernel_launch(void* const* d_in, const int* in_sizes, int n_in,
                              void* d_out, int out_size, void* d_ws, size_t ws_size,
                              hipStream_t stream) {
  (void)in_sizes; (void)n_in; (void)out_size; (void)ws_size;
  const float* bert   = (const float*)d_in[0];
  const float* oenc   = (const float*)d_in[1];
  const float* cosim  = (const float*)d_in[2];
  const float* decemb = (const float*)d_in[3];
  const int*   labels = (const int*)d_in[4];
  const float* gamma  = (const float*)d_in[5];
  const float* beta   = (const float*)d_in[6];
  const float* Wadd   = (const float*)d_in[7];
  const float* badd   = (const float*)d_in[8];
  const float* startt = (const float*)d_in[9];
  const float* endt   = (const float*)d_in[10];
  const float* trans  = (const float*)d_in[11];
  float* out = (float*)d_out;
  char*  wsb = (char*)d_ws;
  ushort* decb   = (ushort*)wsb;                 // [0, 1228800)
  ushort* wtb    = (ushort*)(wsb + 1228800);     // [1228800, 1267200)
  float*  nprob  = (float*)(wsb + 1305600);      // [1305600, 2944000)
  float*  csp    = (float*)(wsb + 2944000);      // [2944000, 4582400)
  float*  traceF = (float*)(wsb + 4582400);      // [4582400, 6687744)
  float*  traceB = (float*)(wsb + 6687744);      // [6687744, 8793088)

  prep_kernel<<<864, 256, 0, stream>>>(decemb, gamma, beta, Wadd, cosim, decb, wtb, csp);
  main_kernel<<<2112, 256, 0, stream>>>(bert, oenc, cosim, gamma, beta, badd, decb, wtb,
                                        csp, startt, endt, trans, nprob, traceF, traceB, out);
  scan_kernel<<<96, 256, 0, stream>>>(nprob, csp, traceF, traceB, labels, startt, endt,
                                      trans, out);
}

// Round 17
// 104.799 us; speedup vs baseline: 1.3798x; 1.0390x over previous
//
#include <hip/hip_runtime.h>
#include <hip/hip_bf16.h>

// NerTr fused pipeline for MI355X (gfx950).  B=32, S=512, D=768, C=25.
// ws layout (bytes):
//   decb  (bf16 32*25*768)    [0, 1228800)
//   wtb   (bf16 25*768)       [1228800, 1267200)
//   nprob (f32 32*512*25)     [1305600, 2944000)
//   csp   (f32 32*512*25)     [2944000, 4582400)
//   traceF(f32 32*16448)      [4582400, 6687744)   viterbi fwd states, stride 64/step
//   traceB(f32 32*16448)      [6687744, 8793088)   viterbi bwd suffix states, stride 64
// out: [0]=loss (f32), [1 + b*512 + t] = viterbi tag (as f32).

#define NEGINF (-1e30f)

__device__ __forceinline__ float rlane(float x, int i) {
  return __int_as_float(__builtin_amdgcn_readlane(__float_as_int(x), i));
}
__device__ __forceinline__ float rfl(float x) {
  return __int_as_float(__builtin_amdgcn_readfirstlane(__float_as_int(x)));
}
template <int CTRL, int RMASK>
__device__ __forceinline__ float dppAdd(float x) {
  return x + __int_as_float(__builtin_amdgcn_update_dpp(
                 0, __float_as_int(x), CTRL, RMASK, 0xF, true));
}
__device__ __forceinline__ float wsum(float v) {
  v = dppAdd<0x111, 0xF>(v);
  v = dppAdd<0x112, 0xF>(v);
  v = dppAdd<0x114, 0xF>(v);
  v = dppAdd<0x118, 0xF>(v);
  v = dppAdd<0x142, 0xA>(v);
  v = dppAdd<0x143, 0xC>(v);
  return rlane(v, 63);
}
__device__ __forceinline__ ushort f2bf(float x) {
  __hip_bfloat16 h = __float2bfloat16(x);
  return *reinterpret_cast<ushort*>(&h);
}
__device__ __forceinline__ void ld12(float* x, const float* p, int lane) {
#pragma unroll
  for (int k = 0; k < 3; k++) {
    float4 v = *(const float4*)(p + (lane + (k << 6)) * 4);
    x[4 * k + 0] = v.x; x[4 * k + 1] = v.y; x[4 * k + 2] = v.z; x[4 * k + 3] = v.w;
  }
}
__device__ __forceinline__ void ld12bf(float* x, const ushort* row, int lane) {
  uint2 d0 = *(const uint2*)((const char*)row + lane * 8);
  uint2 d1 = *(const uint2*)((const char*)row + lane * 8 + 512);
  uint2 d2 = *(const uint2*)((const char*)row + lane * 8 + 1024);
  x[0]  = __uint_as_float(d0.x << 16); x[1]  = __uint_as_float(d0.x & 0xffff0000u);
  x[2]  = __uint_as_float(d0.y << 16); x[3]  = __uint_as_float(d0.y & 0xffff0000u);
  x[4]  = __uint_as_float(d1.x << 16); x[5]  = __uint_as_float(d1.x & 0xffff0000u);
  x[6]  = __uint_as_float(d1.y << 16); x[7]  = __uint_as_float(d1.y & 0xffff0000u);
  x[8]  = __uint_as_float(d2.x << 16); x[9]  = __uint_as_float(d2.x & 0xffff0000u);
  x[10] = __uint_as_float(d2.y << 16); x[11] = __uint_as_float(d2.y & 0xffff0000u);
}

__device__ __forceinline__ float max25(const float c[25]) {
  float m0 = fmaxf(fmaxf(c[0], c[1]), c[2]);
  float m1 = fmaxf(fmaxf(c[3], c[4]), c[5]);
  float m2 = fmaxf(fmaxf(c[6], c[7]), c[8]);
  float m3 = fmaxf(fmaxf(c[9], c[10]), c[11]);
  float m4 = fmaxf(fmaxf(c[12], c[13]), c[14]);
  float m5 = fmaxf(fmaxf(c[15], c[16]), c[17]);
  float m6 = fmaxf(fmaxf(c[18], c[19]), c[20]);
  float m7 = fmaxf(fmaxf(c[21], c[22]), c[23]);
  float n0 = fmaxf(fmaxf(m0, m1), m2);
  float n1 = fmaxf(fmaxf(m3, m4), m5);
  float n2 = fmaxf(fmaxf(m6, m7), c[24]);
  return fmaxf(fmaxf(n0, n1), n2);
}

// argmax over 25, first-index tie-break (jnp semantics) — parallel hist-recompute only
__device__ __forceinline__ void argmax25(const float c[25], float& bv, int& bi) {
  float v[13]; int x[13];
#pragma unroll
  for (int i = 0; i < 12; i++) {
    bool t = c[2 * i + 1] > c[2 * i];
    v[i] = t ? c[2 * i + 1] : c[2 * i];
    x[i] = t ? 2 * i + 1 : 2 * i;
  }
  v[12] = c[24]; x[12] = 24;
  float w[7]; int y[7];
#pragma unroll
  for (int i = 0; i < 6; i++) {
    bool t = v[2 * i + 1] > v[2 * i];
    w[i] = t ? v[2 * i + 1] : v[2 * i];
    y[i] = t ? x[2 * i + 1] : x[2 * i];
  }
  w[6] = v[12]; y[6] = x[12];
  float u[4]; int z[4];
#pragma unroll
  for (int i = 0; i < 3; i++) {
    bool t = w[2 * i + 1] > w[2 * i];
    u[i] = t ? w[2 * i + 1] : w[2 * i];
    z[i] = t ? y[2 * i + 1] : y[2 * i];
  }
  u[3] = w[6]; z[3] = y[6];
  bool t0 = u[1] > u[0]; float a = t0 ? u[1] : u[0]; int ai = t0 ? z[1] : z[0];
  bool t1 = u[3] > u[2]; float b = t1 ? u[3] : u[2]; int bj = t1 ? z[3] : z[2];
  bool t2 = b > a; bv = t2 ? b : a; bi = t2 ? bj : ai;
}

// ---------------- Kernel 1: LN(dec)->bf16 + W transpose->bf16 + softmax(cos_sim) ----------------
__global__ __launch_bounds__(256) void prep_kernel(
    const float* __restrict__ decemb, const float* __restrict__ gamma,
    const float* __restrict__ beta, const float* __restrict__ Wadd,
    const float* __restrict__ cosim,
    ushort* __restrict__ decb, ushort* __restrict__ wtb, float* __restrict__ csp) {
  const int blk = blockIdx.x;
  const int tid = threadIdx.x;
  __shared__ float sa[4], sq[4];
  __shared__ float sem[12800];
  if (blk < 800) {
    const float* in = decemb + (size_t)blk * 768;
    float x0 = in[tid], x1 = in[tid + 256], x2 = in[tid + 512];
    float s = x0 + x1 + x2, q = x0 * x0 + x1 * x1 + x2 * x2;
    float ws_ = wsum(s), wq = wsum(q);
    int w = tid >> 6, ln = tid & 63;
    if (ln == 0) { sa[w] = ws_; sq[w] = wq; }
    __syncthreads();
    float s1 = sa[0] + sa[1] + sa[2] + sa[3];
    float s2 = sq[0] + sq[1] + sq[2] + sq[3];
    float mean = s1 * (1.f / 768.f);
    float rstd = rsqrtf(s2 * (1.f / 768.f) - mean * mean + 1e-5f);
    ushort* o = decb + (size_t)blk * 768;
    o[tid]       = f2bf((x0 - mean) * rstd * gamma[tid]       + beta[tid]);
    o[tid + 256] = f2bf((x1 - mean) * rstd * gamma[tid + 256] + beta[tid + 256]);
    o[tid + 512] = f2bf((x2 - mean) * rstd * gamma[tid + 512] + beta[tid + 512]);
  } else if (blk < 832) {
    int gid = (blk - 800) * 256 + tid;
    for (int e = gid; e < 19200; e += 32 * 256) {
      int d = e / 25, j = e - d * 25;
      wtb[j * 768 + d] = f2bf(Wadd[e]);
    }
  } else {
    const int b = blk - 832;
    const float4* cb4 = (const float4*)(cosim + (size_t)b * 12800);
    float4* em4 = (float4*)sem;
    for (int i = tid; i < 3200; i += 256) em4[i] = cb4[i];
    __syncthreads();
#pragma unroll
    for (int rr = 0; rr < 2; rr++) {
      const int r = tid + (rr << 8);
      float v[25];
#pragma unroll
      for (int k = 0; k < 25; k++) v[k] = sem[r * 25 + k];
      float m01 = v[0];
#pragma unroll
      for (int k = 1; k < 25; k++) m01 = fmaxf(m01, v[k]);
      float s = 0.f;
#pragma unroll
      for (int k = 0; k < 25; k++) { v[k] = __expf(v[k] - m01); s += v[k]; }
      float rinv = __builtin_amdgcn_rcpf(s);
#pragma unroll
      for (int k = 0; k < 25; k++) sem[r * 25 + k] = v[k] * rinv;
    }
    __syncthreads();
    float4* cp4 = (float4*)(csp + (size_t)b * 12800);
    for (int i = tid; i < 3200; i += 256) cp4[i] = em4[i];
  }
}

// ---------------- Kernel 2: Viterbi VALUE scans (bid<64, setprio) + streaming (r12 base) ----------------
__global__ __launch_bounds__(256) void main_kernel(
    const float* __restrict__ bert, const float* __restrict__ oenc,
    const float* __restrict__ cosim, const float* __restrict__ gamma,
    const float* __restrict__ beta, const float* __restrict__ badd,
    const ushort* __restrict__ decb, const ushort* __restrict__ wtb,
    const float* __restrict__ csp, const float* __restrict__ startt,
    const float* __restrict__ endt, const float* __restrict__ trans,
    float* __restrict__ nprob, float* __restrict__ traceF,
    float* __restrict__ traceB, float* __restrict__ out) {
  // union LDS: scan blocks: em 6500 f32 (26000 B); streaming: sdec 38400 B then scatter bufs
  __shared__ ushort sh[19200];
  const int tid = threadIdx.x;
  const int lane = tid & 63;
  const int wid = tid >> 6;
  const int bid = blockIdx.x;

  if (bid < 64) {
    // ======== Viterbi value-only scans, em in LDS, at elevated priority ========
    // setprio(1) reclaims issue slots from co-resident streaming waves (role split:
    // this wave is dependency-bound, they are throughput-bound).
    const bool isFwd = bid < 32;
    const int b = isFwd ? bid : bid - 32;
    const int tl = (lane < 25) ? lane : 24;
    float* em = (float*)sh;  // rows 0..259 (fwd) or 252..511 (bwd)
    {
      const float4* src4 = (const float4*)(csp + (size_t)b * 12800 + (isFwd ? 0 : 6300));
      float4* dst4 = (float4*)em;
#pragma unroll
      for (int i = 0; i < 7; i++) {
        int e = tid + (i << 8);
        if (e < 1625) dst4[e] = src4[e];
      }
    }
    __syncthreads();
    if (wid != 0) return;

    __builtin_amdgcn_s_setprio(1);
    if (isFwd) {  // t = 0..256, em row t at em[t*25]
      float* tf = traceF + (size_t)b * 16448;
      float Tc[25];
#pragma unroll
      for (int i = 0; i < 25; i++) Tc[i] = trans[i * 25 + tl];
      float sc = startt[tl] + em[tl];
      tf[lane] = sc;
      float emA = em[25 + tl], emB = em[50 + tl];
      for (int t = 1; t <= 256; t++) {
        float emC = em[(t + 2) * 25 + tl];
        float s[25], c[25];
#pragma unroll
        for (int i = 0; i < 25; i++) s[i] = rlane(sc, i);
#pragma unroll
        for (int i = 0; i < 25; i++) c[i] = s[i] + Tc[i];
        float bv = max25(c);
        sc = bv + emA;
        tf[t * 64 + lane] = sc;  // fire-and-forget
        emA = emB; emB = emC;
      }
    } else {  // t = 511..257, em row t at em[(t-252)*25]
      float* tb = traceB + (size_t)b * 16448;
      float Tr[25];
#pragma unroll
      for (int j = 0; j < 25; j++) Tr[j] = trans[tl * 25 + j];
      float bwd = endt[tl];
      float emA = em[(511 - 252) * 25 + tl], emB = em[(510 - 252) * 25 + tl];
      for (int t = 511; t >= 257; t--) {
        float emC = em[(t - 2 - 252) * 25 + tl];
        tb[(511 - t) * 64 + lane] = bwd;  // suffix(t+1)
        float u = bwd + emA;
        float s[25], c[25];
#pragma unroll
        for (int j = 0; j < 25; j++) s[j] = rlane(u, j);
#pragma unroll
        for (int j = 0; j < 25; j++) c[j] = s[j] + Tr[j];
        float bv = max25(c);
        bwd = bv;
        emA = emB; emB = emC;
      }
      tb[255 * 64 + lane] = bwd;  // suffix(257)
    }
    __builtin_amdgcn_s_setprio(0);
    return;
  }

  // ======== streaming path: 2 rows/wave, sdec staged in LDS (r12 base) ========
  if (bid == 64 && tid == 0) out[0] = 0.f;  // loss accumulator (scan adds later)
  const int idx = bid - 64;
  const int swz = (idx & 7) * 256 + (idx >> 3);  // bijective XCD swizzle (2048 = 8x256)
  const int b = swz >> 6;
  const int rowg = b * 512 + ((swz & 63) << 3) + (wid << 1);

  // stage decb[b] -> sh (2400 uint4, guarded)
  {
    const uint4* src = (const uint4*)(decb + (size_t)b * 19200);
    uint4* dst = (uint4*)sh;
#pragma unroll
    for (int i = 0; i < 10; i++) {
      int e = tid + (i << 8);
      if (e < 2400) dst[e] = src[e];
    }
  }
  float g[12], bbv[12];
  ld12(g, gamma, lane);
  ld12(bbv, beta, lane);
  float acc[2][12];
  ld12(acc[0], bert + (size_t)(rowg + 0) * 768, lane);
  ld12(acc[1], bert + (size_t)(rowg + 1) * 768, lane);
  float cs0 = (lane < 25) ? cosim[(size_t)(rowg + 0) * 25 + lane] : 0.f;
  float cs1 = (lane < 25) ? cosim[(size_t)(rowg + 1) * 25 + lane] : 0.f;
  __syncthreads();

  // Phase A: acc = LN(bert)
#pragma unroll
  for (int r = 0; r < 2; r++) {
    float s = 0.f, q = 0.f;
#pragma unroll
    for (int e = 0; e < 12; e++) { s += acc[r][e]; q += acc[r][e] * acc[r][e]; }
    s = wsum(s); q = wsum(q);
    float mean = s * (1.f / 768.f);
    float rstd = rsqrtf(q * (1.f / 768.f) - mean * mean + 1e-5f);
#pragma unroll
    for (int e = 0; e < 12; e++) acc[r][e] = (acc[r][e] - mean) * rstd * g[e] + bbv[e];
  }

  // Phase B: acc += cos_sim @ dec  (LDS bf16)
  const char* sd = (const char*)sh;
#pragma unroll 5
  for (int c = 0; c < 25; c++) {
    uint2 d0 = *(const uint2*)(sd + c * 1536 + lane * 8);
    uint2 d1 = *(const uint2*)(sd + c * 1536 + lane * 8 + 512);
    uint2 d2 = *(const uint2*)(sd + c * 1536 + lane * 8 + 1024);
    float dv[12];
    dv[0]  = __uint_as_float(d0.x << 16); dv[1]  = __uint_as_float(d0.x & 0xffff0000u);
    dv[2]  = __uint_as_float(d0.y << 16); dv[3]  = __uint_as_float(d0.y & 0xffff0000u);
    dv[4]  = __uint_as_float(d1.x << 16); dv[5]  = __uint_as_float(d1.x & 0xffff0000u);
    dv[6]  = __uint_as_float(d1.y << 16); dv[7]  = __uint_as_float(d1.y & 0xffff0000u);
    dv[8]  = __uint_as_float(d2.x << 16); dv[9]  = __uint_as_float(d2.x & 0xffff0000u);
    dv[10] = __uint_as_float(d2.y << 16); dv[11] = __uint_as_float(d2.y & 0xffff0000u);
    float f0 = rlane(cs0, c), f1 = rlane(cs1, c);
#pragma unroll
    for (int e = 0; e < 12; e++) {
      acc[0][e] = fmaf(f0, dv[e], acc[0][e]);
      acc[1][e] = fmaf(f1, dv[e], acc[1][e]);
    }
  }

  // += oenc
#pragma unroll
  for (int r = 0; r < 2; r++) {
    float y[12];
    ld12(y, oenc + (size_t)(rowg + r) * 768, lane);
#pragma unroll
    for (int e = 0; e < 12; e++) acc[r][e] += y[e];
  }

  // Phase C: acc = relu(LN(acc))
#pragma unroll
  for (int r = 0; r < 2; r++) {
    float s = 0.f, q = 0.f;
#pragma unroll
    for (int e = 0; e < 12; e++) { s += acc[r][e]; q += acc[r][e] * acc[r][e]; }
    s = wsum(s); q = wsum(q);
    float mean = s * (1.f / 768.f);
    float rstd = rsqrtf(q * (1.f / 768.f) - mean * mean + 1e-5f);
#pragma unroll
    for (int e = 0; e < 12; e++)
      acc[r][e] = fmaxf((acc[r][e] - mean) * rstd * g[e] + bbv[e], 0.f);
  }

  __syncthreads();  // done reading sdec -> reuse sh as scatter scratch

  // Phase D: logits, bf16 wt, unroll-5 pipelined, immediate wave-private LDS scatter
  ushort* scw0 = sh + wid * 3400;
  ushort* scw1 = scw0 + 1700;
#pragma unroll 5
  for (int j = 0; j < 25; j++) {
    float wv[12];
    ld12bf(wv, wtb + j * 768, lane);
    float p0 = 0.f, p1 = 0.f;
#pragma unroll
    for (int e = 0; e < 12; e++) {
      p0 = fmaf(acc[0][e], wv[e], p0);
      p1 = fmaf(acc[1][e], wv[e], p1);
    }
    scw0[j * 68 + lane] = f2bf(p0);
    scw1[j * 68 + lane] = f2bf(p1);
  }
  float bav = (lane < 25) ? badd[lane] : 0.f;
  const int jj = (lane < 25) ? lane : 24;
#pragma unroll
  for (int r = 0; r < 2; r++) {
    const ushort* scw = (r == 0) ? scw0 : scw1;
    float lg = bav;
#pragma unroll
    for (int i = 0; i < 16; i++) {
      uint2 u = *(const uint2*)(scw + jj * 68 + i * 4);
      lg += __uint_as_float(u.x << 16);
      lg += __uint_as_float(u.x & 0xffff0000u);
      lg += __uint_as_float(u.y << 16);
      lg += __uint_as_float(u.y & 0xffff0000u);
    }
    float v = (lane < 25) ? lg : NEGINF;
    float m = rfl(lg);  // stability offset cancels analytically
    float e = __expf(v - m);
    float s = wsum(e);
    if (lane < 25) nprob[(size_t)(rowg + r) * 25 + lane] = e * __builtin_amdgcn_rcpf(s);
  }
}

// ---------------- Kernel 3: CRF linear (0..31) || Viterbi finish (32..95) ----------------
__global__ __launch_bounds__(256) void scan_kernel(
    const float* __restrict__ nprob, const float* __restrict__ csp,
    const float* __restrict__ traceF, const float* __restrict__ traceB,
    const int* __restrict__ labels, const float* __restrict__ startt,
    const float* __restrict__ endt, const float* __restrict__ trans,
    float* __restrict__ out) {
  const int tid = threadIdx.x, lane = tid & 63, wid = tid >> 6;
  const int blk = blockIdx.x;
  const int tl = (lane < 25) ? lane : 24;
  __shared__ __align__(16) unsigned char shraw[13568];

  if (blk < 32) {
    // ======== CRF NLL, linear-domain scans with pow2 renorm ========
    const int b = blk;
    const float* np = nprob + (size_t)b * 12800;
    float* fp = (float*)shraw;
    float* fq = fp + 32;
    float* snum = fq + 32;
    int* sKf = (int*)(snum + 1);
    int* sKb = sKf + 1;
    if (wid == 0) {
      float Mc[25];
#pragma unroll
      for (int i = 0; i < 25; i++) Mc[i] = __expf(trans[i * 25 + tl]);
      float p = (lane < 25) ? __expf(startt[lane]) * np[lane] : 0.f;
      float eA = np[25 + tl], eB = np[50 + tl];
      int K = 0;
      for (int t = 1; t <= 256; t++) {
        float eC = np[(t + 2) * 25 + tl];
        float s[25];
#pragma unroll
        for (int i = 0; i < 25; i++) s[i] = rlane(p, i);
        float a0 = 0, a1 = 0, a2 = 0, a3 = 0, a4 = 0;
#pragma unroll
        for (int i = 0; i < 25; i += 5) {
          a0 = fmaf(s[i + 0], Mc[i + 0], a0);
          a1 = fmaf(s[i + 1], Mc[i + 1], a1);
          a2 = fmaf(s[i + 2], Mc[i + 2], a2);
          a3 = fmaf(s[i + 3], Mc[i + 3], a3);
          a4 = fmaf(s[i + 4], Mc[i + 4], a4);
        }
        float acc = ((a0 + a1) + (a2 + a3)) + a4;
        if ((t & 7) == 0) {
          unsigned mu = 0;
#pragma unroll
          for (int i = 0; i < 25; i++) {
            unsigned ub = __float_as_uint(s[i]);
            mu = (ub > mu) ? ub : mu;
          }
          int e8 = (int)((mu >> 23) & 0xFF);
          acc *= __uint_as_float((unsigned)(254 - e8) << 23);
          K += 127 - e8;
        }
        p = (lane < 25) ? acc * eA : 0.f;
        eA = eB; eB = eC;
      }
      if (lane < 25) fp[lane] = p;
      if (lane == 0) *sKf = K;
    } else if (wid == 1) {
      float MrE[25];
#pragma unroll
      for (int j = 0; j < 25; j++) MrE[j] = __expf(trans[tl * 25 + j]);
      float q = (lane < 25) ? __expf(endt[lane]) : 0.f;
      float eA = np[511 * 25 + tl], eB = np[510 * 25 + tl];
      int K = 0;
      for (int t = 511; t >= 257; t--) {
        float eC = np[(t - 2) * 25 + tl];
        float u = q * eA;
        float s[25];
#pragma unroll
        for (int j = 0; j < 25; j++) s[j] = rlane(u, j);
        float a0 = 0, a1 = 0, a2 = 0, a3 = 0, a4 = 0;
#pragma unroll
        for (int j = 0; j < 25; j += 5) {
          a0 = fmaf(s[j + 0], MrE[j + 0], a0);
          a1 = fmaf(s[j + 1], MrE[j + 1], a1);
          a2 = fmaf(s[j + 2], MrE[j + 2], a2);
          a3 = fmaf(s[j + 3], MrE[j + 3], a3);
          a4 = fmaf(s[j + 4], MrE[j + 4], a4);
        }
        float acc = ((a0 + a1) + (a2 + a3)) + a4;
        if ((t & 7) == 0) {
          unsigned mu = 0;
#pragma unroll
          for (int j = 0; j < 25; j++) {
            unsigned ub = __float_as_uint(s[j]);
            mu = (ub > mu) ? ub : mu;
          }
          int e8 = (int)((mu >> 23) & 0xFF);
          acc *= __uint_as_float((unsigned)(254 - e8) << 23);
          K += 127 - e8;
        }
        q = (lane < 25) ? acc : 0.f;
        eA = eB; eB = eC;
      }
      if (lane < 25) fq[lane] = q;
      if (lane == 0) *sKb = K;
    } else if (wid == 2) {
      float a = 0.f;
      const int* lb = labels + b * 512;
      for (int t = lane; t < 512; t += 64) a += __logf(np[t * 25 + lb[t]]);
      for (int t = lane; t < 511; t += 64) a += trans[lb[t] * 25 + lb[t + 1]];
      a = wsum(a);
      if (lane == 0) *snum = a + startt[lb[0]] + endt[lb[511]];
    }
    __syncthreads();
    if (wid == 0) {
      float z = (lane < 25) ? fp[lane] * fq[lane] : 0.f;
      z = wsum(z);
      float logZ = __logf(z) - (float)(*sKf + *sKb) * 0.6931471805599453f;
      float llh = *snum - logZ;
      if (lane == 0) atomicAdd(out, -llh * (1.f / 32.f));
    }
    return;
  }

  // ======== Viterbi finish: parallel hist recompute + backtrace ========
  const int vb = blk - 32;          // 0..63
  const int b = vb & 31;
  const bool isFwd = vb < 32;
  unsigned char* hist = shraw;      // [513][26] bytes
  const float* tf = traceF + (size_t)b * 16448;
  const float* tb = traceB + (size_t)b * 16448;

  if (isFwd) {
    float Tc[25];
#pragma unroll
    for (int i = 0; i < 25; i++) Tc[i] = trans[i * 25 + tl];
    int t0 = 1 + (wid << 6);
    float vA = tf[(t0 - 1) * 64 + tl];
    for (int n = 0; n < 64; n++) {
      int t = t0 + n;
      float vB = (n < 63) ? tf[t * 64 + tl] : 0.f;
      float s[25], c[25];
#pragma unroll
      for (int i = 0; i < 25; i++) s[i] = rlane(vA, i);
#pragma unroll
      for (int i = 0; i < 25; i++) c[i] = s[i] + Tc[i];
      float bv; int bi;
      argmax25(c, bv, bi);
      if (lane < 25) hist[t * 26 + lane] = (unsigned char)bi;
      vA = vB;
    }
  } else {
    float Tr[25];
#pragma unroll
    for (int j = 0; j < 25; j++) Tr[j] = trans[tl * 25 + j];
    const float* cb = csp + (size_t)b * 12800;
    int t0 = 257 + (wid << 6);
    float tA = (t0 <= 511) ? tb[(511 - t0) * 64 + tl] : 0.f;
    float eA = (t0 <= 511) ? cb[t0 * 25 + tl] : 0.f;
    for (int n = 0; n < 64; n++) {
      int t = t0 + n;
      if (t > 511) break;
      float tBn = (t < 511) ? tb[(511 - t - 1) * 64 + tl] : 0.f;
      float eBn = (t < 511) ? cb[(t + 1) * 25 + tl] : 0.f;
      float u = tA + eA;
      float s[25], c[25];
#pragma unroll
      for (int j = 0; j < 25; j++) s[j] = rlane(u, j);
#pragma unroll
      for (int j = 0; j < 25; j++) c[j] = s[j] + Tr[j];
      float bv; int bj;
      argmax25(c, bv, bj);
      if (lane < 25) hist[t * 26 + lane] = (unsigned char)bj;
      tA = tBn; eA = eBn;
    }
  }
  __syncthreads();
  if (wid == 0) {
    float fv = (lane < 25) ? tf[256 * 64 + lane] + tb[255 * 64 + lane] : NEGINF;
    int idx = lane;
#pragma unroll
    for (int m = 32; m >= 1; m >>= 1) {
      float ov = __shfl_xor(fv, m); int oi = __shfl_xor(idx, m);
      if (ov > fv || (ov == fv && oi < idx)) { fv = ov; idx = oi; }
    }
    int cur = idx;  // uniform
    float* path = out + 1 + (size_t)b * 512;
    if (isFwd) {
      if (lane == 0) path[256] = (float)cur;
      int h = (lane < 25) ? hist[256 * 26 + lane] : 0;
      for (int t = 256; t >= 1; t--) {
        int hn = (t > 1 && lane < 25) ? hist[(t - 1) * 26 + lane] : 0;
        int prev = __builtin_amdgcn_readlane(h, cur);
        if (lane == 0) path[t - 1] = (float)prev;
        cur = prev; h = hn;
      }
    } else {
      int h = (lane < 25) ? hist[257 * 26 + lane] : 0;
      for (int t = 257; t <= 511; t++) {
        int hn = (t < 511 && lane < 25) ? hist[(t + 1) * 26 + lane] : 0;
        int nx = __builtin_amdgcn_readlane(h, cur);
        if (lane == 0) path[t] = (float)nx;
        cur = nx; h = hn;
      }
    }
  }
}

extern "C" void kernel_launch(void* const* d_in, const int* in_sizes, int n_in,
                              void* d_out, int out_size, void* d_ws, size_t ws_size,
                              hipStream_t stream) {
  (void)in_sizes; (void)n_in; (void)out_size; (void)ws_size;
  const float* bert   = (const float*)d_in[0];
  const float* oenc   = (const float*)d_in[1];
  const float* cosim  = (const float*)d_in[2];
  const float* decemb = (const float*)d_in[3];
  const int*   labels = (const int*)d_in[4];
  const float* gamma  = (const float*)d_in[5];
  const float* beta   = (const float*)d_in[6];
  const float* Wadd   = (const float*)d_in[7];
  const float* badd   = (const float*)d_in[8];
  const float* startt = (const float*)d_in[9];
  const float* endt   = (const float*)d_in[10];
  const float* trans  = (const float*)d_in[11];
  float* out = (float*)d_out;
  char*  wsb = (char*)d_ws;
  ushort* decb   = (ushort*)wsb;                 // [0, 1228800)
  ushort* wtb    = (ushort*)(wsb + 1228800);     // [1228800, 1267200)
  float*  nprob  = (float*)(wsb + 1305600);      // [1305600, 2944000)
  float*  csp    = (float*)(wsb + 2944000);      // [2944000, 4582400)
  float*  traceF = (float*)(wsb + 4582400);      // [4582400, 6687744)
  float*  traceB = (float*)(wsb + 6687744);      // [6687744, 8793088)

  prep_kernel<<<864, 256, 0, stream>>>(decemb, gamma, beta, Wadd, cosim, decb, wtb, csp);
  main_kernel<<<2112, 256, 0, stream>>>(bert, oenc, cosim, gamma, beta, badd, decb, wtb,
                                        csp, startt, endt, trans, nprob, traceF, traceB, out);
  scan_kernel<<<96, 256, 0, stream>>>(nprob, csp, traceF, traceB, labels, startt, endt,
                                      trans, out);
}